// Round 10
// baseline (694.981 us; speedup 1.0000x reference)
//
#include <hip/hip_runtime.h>

#define KK 27

typedef short bf16x8 __attribute__((ext_vector_type(8)));   // 8 bf16 in 4 VGPRs
typedef float f32x4  __attribute__((ext_vector_type(4)));

__device__ inline unsigned short f2bf(float f) {            // RNE fp32 -> bf16
    unsigned u = __float_as_uint(f);
    unsigned r = u + 0x7fffu + ((u >> 16) & 1u);
    return (unsigned short)(r >> 16);
}

// ---- Kernel 1: fused prep ----
__global__ __launch_bounds__(256) void prep_k(const float* __restrict__ in,
                                              const float* __restrict__ w,
                                              unsigned short* __restrict__ xTb,
                                              unsigned short* __restrict__ wTb,
                                              float* __restrict__ tot, int N) {
    const int bx = blockIdx.x;
    if (bx < KK) {
        if (bx == 0 && threadIdx.x < 64) tot[threadIdx.x] = 0.f;
        for (int i = threadIdx.x; i < 1024; i += 256) {
            int cin = i >> 5, cout = i & 31;
            wTb[bx * 1024 + cout * 32 + cin] = f2bf(w[bx * 1024 + cin * 32 + cout]);
        }
        return;
    }
    __shared__ float tile[32][33];
    int n0 = (bx - KK) * 32;
    int tx = threadIdx.x & 31;
    int ty = threadIdx.x >> 5;  // 0..7
#pragma unroll
    for (int c = ty; c < 32; c += 8) {
        int n = n0 + tx;
        tile[c][tx] = (n < N) ? in[(long)c * N + n] : 0.f;
    }
    __syncthreads();
#pragma unroll
    for (int nn = ty; nn < 32; nn += 8) {
        int n = n0 + nn;
        if (n < N) xTb[(long)n * 32 + tx] = f2bf(tile[tx][nn]);
    }
}

// ---- Kernel 2: MFMA conv, tap-split across 4 waves ----
// Block = 256 threads = 4 waves, ALL covering the same 32 nodes; wave wv does
// taps [7wv, 7wv+7) (6 for wv=3). Per-wave serial chain: ~7 taps instead of 27,
// and total waves = 12500 (~48/CU demanded, ~16/CU resident) -> latency hidden
// by TLP, not per-wave pipelining (which rounds 4/5/7/9 showed doesn't survive
// this compiler). acc=16 VGPRs; 1-stage prefetch only; small LDS (16.9 KB).
__global__ __launch_bounds__(256, 4) void conv_k(const unsigned short* __restrict__ xTb,
                                                 const int* __restrict__ neigh,
                                                 const unsigned short* __restrict__ wTb,
                                                 float* __restrict__ y,    // [32][N]
                                                 float* __restrict__ tot,  // [64]
                                                 int N) {
    __shared__ float lacc[4][32][33];   // [wave][node][cout], pad -> conflict-free reads

    const int tid  = threadIdx.x;
    const int L    = tid & 63;
    const int wv   = tid >> 6;         // tap group
    const int r16  = L & 15;
    const int quad = L >> 4;           // 0..3
    const int base = blockIdx.x * 32;
    const int n0c  = min(base + r16, N - 1);
    const int n1c  = min(base + 16 + r16, N - 1);
    const long nb0 = (long)n0c * KK;
    const long nb1 = (long)n1c * KK;

    const int kbeg = wv * 7;
    const int cnt  = (wv == 3) ? 6 : 7;

    f32x4 acc00 = {0.f, 0.f, 0.f, 0.f};
    f32x4 acc01 = acc00, acc10 = acc00, acc11 = acc00;

    // prologue: first tap's gathers + next tap's indices
    int m0 = neigh[nb0 + kbeg];
    int m1 = neigh[nb1 + kbeg];
    bf16x8 a0 = *(const bf16x8*)(xTb + (long)m0 * 32 + quad * 8);
    bf16x8 a1 = *(const bf16x8*)(xTb + (long)m1 * 32 + quad * 8);
    bf16x8 b0 = *(const bf16x8*)(wTb + kbeg * 1024 + r16 * 32 + quad * 8);
    bf16x8 b1 = *(const bf16x8*)(wTb + kbeg * 1024 + (16 + r16) * 32 + quad * 8);
    int j0 = neigh[nb0 + kbeg + 1];
    int j1 = neigh[nb1 + kbeg + 1];

#pragma unroll 1
    for (int t = 0; t < cnt; ++t) {
        bf16x8 na0, na1, pb0, pb1;
        if (t + 1 < cnt) {
            na0 = *(const bf16x8*)(xTb + (long)j0 * 32 + quad * 8);
            na1 = *(const bf16x8*)(xTb + (long)j1 * 32 + quad * 8);
            const unsigned short* wn = wTb + (kbeg + t + 1) * 1024;
            pb0 = *(const bf16x8*)(wn + r16 * 32 + quad * 8);
            pb1 = *(const bf16x8*)(wn + (16 + r16) * 32 + quad * 8);
            int kk = min(kbeg + t + 2, KK - 1);
            j0 = neigh[nb0 + kk];
            j1 = neigh[nb1 + kk];
        }

        acc00 = __builtin_amdgcn_mfma_f32_16x16x32_bf16(a0, b0, acc00, 0, 0, 0);
        acc01 = __builtin_amdgcn_mfma_f32_16x16x32_bf16(a0, b1, acc01, 0, 0, 0);
        acc10 = __builtin_amdgcn_mfma_f32_16x16x32_bf16(a1, b0, acc10, 0, 0, 0);
        acc11 = __builtin_amdgcn_mfma_f32_16x16x32_bf16(a1, b1, acc11, 0, 0, 0);

        if (t + 1 < cnt) {
            a0 = na0; a1 = na1; b0 = pb0; b1 = pb1;
        }
    }

    // stash this wave's partial C in LDS
    // C/D layout: cout = r16 (+16 for B1 tiles), node-in-tile = quad*4 + r
#pragma unroll
    for (int r = 0; r < 4; ++r) {
        lacc[wv][quad * 4 + r][r16]           = acc00[r];
        lacc[wv][quad * 4 + r][16 + r16]      = acc01[r];
        lacc[wv][16 + quad * 4 + r][r16]      = acc10[r];
        lacc[wv][16 + quad * 4 + r][16 + r16] = acc11[r];
    }
    __syncthreads();

    // combine 4 tap-group partials; store y coalesced; BN partials via atomics
    const int node = tid & 31;
    const int g    = tid >> 5;      // 0..7 (wave w holds g = 2w, 2w+1)
    const int gn   = base + node;
#pragma unroll
    for (int j = 0; j < 4; ++j) {
        const int cout = g + j * 8;
        float v = lacc[0][node][cout] + lacc[1][node][cout]
                + lacc[2][node][cout] + lacc[3][node][cout];
        if (gn < N) y[(long)cout * N + gn] = v;
        else        v = 0.f;
        float s = v;
        float q = v * v;
#pragma unroll
        for (int off = 1; off < 32; off <<= 1) {   // reduce within each 32-lane half
            s += __shfl_xor(s, off, 64);
            q += __shfl_xor(q, off, 64);
        }
        if ((L & 31) == 0) {
            atomicAdd(tot + cout,      s);
            atomicAdd(tot + 32 + cout, q);
        }
    }
}

// ---- Kernel 3: finalize stats + normalize y in place ----
__global__ __launch_bounds__(256) void norm_k(float* __restrict__ y,
                                              const float* __restrict__ tot,
                                              const float* __restrict__ gamma,
                                              const float* __restrict__ beta, int N) {
    const int d = blockIdx.y;
    const float mean = tot[d] / (float)N;
    const float var  = tot[d + 32] / (float)N - mean * mean;
    const float sc   = gamma[d] * rsqrtf(var + 1e-3f);
    const float sh   = beta[d] - mean * sc;

    int i = blockIdx.x * blockDim.x + threadIdx.x;
    int base = i * 4;
    if (base + 3 < N) {
        float4* p = (float4*)(y + (long)d * N + base);
        float4 v = *p;
        v.x = fmaf(v.x, sc, sh);
        v.y = fmaf(v.y, sc, sh);
        v.z = fmaf(v.z, sc, sh);
        v.w = fmaf(v.w, sc, sh);
        *p = v;
    } else if (base < N) {
        for (int t = base; t < N; ++t) y[(long)d * N + t] = fmaf(y[(long)d * N + t], sc, sh);
    }
}

// ---- launcher ----
extern "C" void kernel_launch(void* const* d_in, const int* in_sizes, int n_in,
                              void* d_out, int out_size, void* d_ws, size_t ws_size,
                              hipStream_t stream) {
    const float* data_in = (const float*)d_in[0];
    const int*   neigh   = (const int*)d_in[1];
    const float* weight  = (const float*)d_in[2];
    const float* gamma   = (const float*)d_in[3];
    const float* beta    = (const float*)d_in[4];
    float* out = (float*)d_out;

    const int N = in_sizes[1] / KK;
    const int nblk32 = (N + 31) / 32;        // x-prep tiles AND conv blocks

    char* ws = (char*)d_ws;
    unsigned short* xTb = (unsigned short*)ws;                     // N*32 bf16
    unsigned short* wTb = (unsigned short*)(ws + (size_t)N * 64);  // 27*1024 bf16
    float* tot = (float*)(ws + (size_t)N * 64 + 55296);            // 64 floats

    prep_k<<<KK + nblk32, 256, 0, stream>>>(data_in, weight, xTb, wTb, tot, N);
    conv_k<<<nblk32, 256, 0, stream>>>(xTb, neigh, wTb, out, tot, N);
    dim3 ngrid(((N + 3) / 4 + 255) / 256, 32);
    norm_k<<<ngrid, 256, 0, stream>>>(out, tot, gamma, beta, N);
}

// Round 11
// 145.978 us; speedup vs baseline: 4.7608x; 4.7608x over previous
//
#include <hip/hip_runtime.h>

#define KK 27

typedef short bf16x8 __attribute__((ext_vector_type(8)));   // 8 bf16 in 4 VGPRs
typedef float f32x4  __attribute__((ext_vector_type(4)));

__device__ inline unsigned short f2bf(float f) {            // RNE fp32 -> bf16
    unsigned u = __float_as_uint(f);
    unsigned r = u + 0x7fffu + ((u >> 16) & 1u);
    return (unsigned short)(r >> 16);
}

// ---- Kernel 1: fused prep ----
// blocks [0, KK): weight [27][cin][cout] fp32 -> wTb [27][cout][cin] bf16
// blocks [KK, ...): x [32][N] fp32 -> xTb [N][32] bf16 (transpose + cast)
__global__ __launch_bounds__(256) void prep_k(const float* __restrict__ in,
                                              const float* __restrict__ w,
                                              unsigned short* __restrict__ xTb,
                                              unsigned short* __restrict__ wTb,
                                              int N) {
    const int bx = blockIdx.x;
    if (bx < KK) {
        for (int i = threadIdx.x; i < 1024; i += 256) {
            int cin = i >> 5, cout = i & 31;
            wTb[bx * 1024 + cout * 32 + cin] = f2bf(w[bx * 1024 + cin * 32 + cout]);
        }
        return;
    }
    __shared__ float tile[32][33];
    int n0 = (bx - KK) * 32;
    int tx = threadIdx.x & 31;
    int ty = threadIdx.x >> 5;  // 0..7
#pragma unroll
    for (int c = ty; c < 32; c += 8) {
        int n = n0 + tx;
        tile[c][tx] = (n < N) ? in[(long)c * N + n] : 0.f;
    }
    __syncthreads();
#pragma unroll
    for (int nn = ty; nn < 32; nn += 8) {
        int n = n0 + nn;
        if (n < N) xTb[(long)n * 32 + tx] = f2bf(tile[tx][nn]);
    }
}

// ---- Kernel 2: MFMA conv — round-6 structure, halved M-tile ----
// One INDEPENDENT wave per 16 nodes (6252 waves = 2x round 6's TLP), 4 waves
// per block with disjoint node sets (no sharing, no __syncthreads, no atomics).
// Full 27-tap "#pragma unroll 1" loop, 1-stage prefetch, k is a pure loop
// counter (block-uniform weight addressing). acc=8 + frags 12 + prefetch 12
// ~= 40 live VGPRs — safely inside the 64-VGPR bucket the allocator targets.
__global__ __launch_bounds__(256) void conv_k(const unsigned short* __restrict__ xTb,
                                              const int* __restrict__ neigh,
                                              const unsigned short* __restrict__ wTb,
                                              float* __restrict__ y,        // [32][N]
                                              float* __restrict__ partial,  // [64][nrows]
                                              int N, int nrows) {
    __shared__ float ct[4][16][33];    // per-wave transpose buffer (no block sync)

    const int tid   = threadIdx.x;
    const int L     = tid & 63;
    const int wv    = tid >> 6;
    const int r16   = L & 15;
    const int quad  = L >> 4;          // 0..3
    const int base2 = blockIdx.x * 64 + wv * 16;   // this wave's 16 nodes
    const int nc    = min(base2 + r16, N - 1);     // clamped (masked in epilogue)
    const long nb   = (long)nc * KK;

    f32x4 acc0 = {0.f, 0.f, 0.f, 0.f};   // couts 0..15
    f32x4 acc1 = acc0;                    // couts 16..31

    // prologue: tap 0 gather + weights, tap 1 index
    int m = neigh[nb];
    bf16x8 a  = *(const bf16x8*)(xTb + (long)m * 32 + quad * 8);
    bf16x8 b0 = *(const bf16x8*)(wTb + r16 * 32 + quad * 8);
    bf16x8 b1 = *(const bf16x8*)(wTb + (16 + r16) * 32 + quad * 8);
    int j = neigh[nb + 1];

#pragma unroll 1
    for (int k = 0; k < KK; ++k) {
        bf16x8 na, pb0, pb1;
        if (k + 1 < KK) {
            na = *(const bf16x8*)(xTb + (long)j * 32 + quad * 8);
            const unsigned short* wn = wTb + (k + 1) * 1024;
            pb0 = *(const bf16x8*)(wn + r16 * 32 + quad * 8);
            pb1 = *(const bf16x8*)(wn + (16 + r16) * 32 + quad * 8);
            j = neigh[nb + min(k + 2, KK - 1)];
        }

        acc0 = __builtin_amdgcn_mfma_f32_16x16x32_bf16(a, b0, acc0, 0, 0, 0);
        acc1 = __builtin_amdgcn_mfma_f32_16x16x32_bf16(a, b1, acc1, 0, 0, 0);

        if (k + 1 < KK) { a = na; b0 = pb0; b1 = pb1; }
    }

    // zero out-of-range nodes (C/D layout: cout = r16 (+16), node = quad*4+r)
#pragma unroll
    for (int r = 0; r < 4; ++r) {
        if (base2 + quad * 4 + r >= N) { acc0[r] = 0.f; acc1[r] = 0.f; }
    }

    // BN partials: sum over this wave's 16 nodes -> partial[cout][wrow]
    float s0 = 0.f, q0 = 0.f, s1 = 0.f, q1 = 0.f;
#pragma unroll
    for (int r = 0; r < 4; ++r) {
        s0 += acc0[r];  q0 += acc0[r] * acc0[r];
        s1 += acc1[r];  q1 += acc1[r] * acc1[r];
    }
    s0 += __shfl_xor(s0, 16, 64); q0 += __shfl_xor(q0, 16, 64);
    s1 += __shfl_xor(s1, 16, 64); q1 += __shfl_xor(q1, 16, 64);
    s0 += __shfl_xor(s0, 32, 64); q0 += __shfl_xor(q0, 32, 64);
    s1 += __shfl_xor(s1, 32, 64); q1 += __shfl_xor(q1, 32, 64);
    const int wrow = blockIdx.x * 4 + wv;
    if (L < 16) {
        partial[(long)L * nrows + wrow]        = s0;
        partial[(long)(L + 16) * nrows + wrow] = s1;
        partial[(long)(L + 32) * nrows + wrow] = q0;
        partial[(long)(L + 48) * nrows + wrow] = q1;
    }

    // per-wave LDS transpose -> coalesced y stores ([cout][node])
#pragma unroll
    for (int r = 0; r < 4; ++r) {
        ct[wv][quad * 4 + r][r16]      = acc0[r];
        ct[wv][quad * 4 + r][16 + r16] = acc1[r];
    }
    asm volatile("s_waitcnt lgkmcnt(0)" ::: "memory");  // wave-internal LDS w->r
    const int node  = L & 15;
    const int cbase = (L >> 4) * 8;
    const int gn = base2 + node;
    if (gn < N) {
#pragma unroll
        for (int c = 0; c < 8; ++c) {
            const int cout = cbase + c;
            y[(long)cout * N + gn] = ct[wv][node][cout];
        }
    }
}

// ---- Kernel 3: column reduce partial[64][nrows] -> tot[64] ----
__global__ __launch_bounds__(256) void stats1_k(const float* __restrict__ partial,
                                                int nrows, float* __restrict__ tot) {
    __shared__ float red[256];
    const int col = blockIdx.x;  // 0..63
    const float* row = partial + (long)col * nrows;
    float s = 0.f;
    for (int r = threadIdx.x; r < nrows; r += 256) s += row[r];
    red[threadIdx.x] = s;
    __syncthreads();
    for (int w = 128; w >= 64; w >>= 1) {
        if (threadIdx.x < w) red[threadIdx.x] += red[threadIdx.x + w];
        __syncthreads();
    }
    if (threadIdx.x < 64) {
        float v = red[threadIdx.x];
#pragma unroll
        for (int off = 1; off < 64; off <<= 1) v += __shfl_xor(v, off, 64);
        if (threadIdx.x == 0) tot[col] = v;
    }
}

// ---- Kernel 4: finalize stats + normalize y in place ----
__global__ __launch_bounds__(256) void norm_k(float* __restrict__ y,
                                              const float* __restrict__ tot,
                                              const float* __restrict__ gamma,
                                              const float* __restrict__ beta, int N) {
    const int d = blockIdx.y;
    const float mean = tot[d] / (float)N;
    const float var  = tot[d + 32] / (float)N - mean * mean;
    const float sc   = gamma[d] * rsqrtf(var + 1e-3f);
    const float sh   = beta[d] - mean * sc;

    int i = blockIdx.x * blockDim.x + threadIdx.x;
    int base = i * 4;
    if (base + 3 < N) {
        float4* p = (float4*)(y + (long)d * N + base);
        float4 v = *p;
        v.x = fmaf(v.x, sc, sh);
        v.y = fmaf(v.y, sc, sh);
        v.z = fmaf(v.z, sc, sh);
        v.w = fmaf(v.w, sc, sh);
        *p = v;
    } else if (base < N) {
        for (int t = base; t < N; ++t) y[(long)d * N + t] = fmaf(y[(long)d * N + t], sc, sh);
    }
}

// ---- launcher ----
extern "C" void kernel_launch(void* const* d_in, const int* in_sizes, int n_in,
                              void* d_out, int out_size, void* d_ws, size_t ws_size,
                              hipStream_t stream) {
    const float* data_in = (const float*)d_in[0];
    const int*   neigh   = (const int*)d_in[1];
    const float* weight  = (const float*)d_in[2];
    const float* gamma   = (const float*)d_in[3];
    const float* beta    = (const float*)d_in[4];
    float* out = (float*)d_out;

    const int N = in_sizes[1] / KK;
    const int nblk32 = (N + 31) / 32;        // x-prep tiles
    const int nblk64 = (N + 63) / 64;        // conv blocks (4 waves x 16 nodes)
    const int nrows  = nblk64 * 4;           // one partial row per wave

    char* ws = (char*)d_ws;
    unsigned short* xTb = (unsigned short*)ws;                     // N*32 bf16
    unsigned short* wTb = (unsigned short*)(ws + (size_t)N * 64);  // 27*1024 bf16
    float* partial = (float*)(ws + (size_t)N * 64 + 55296);        // 64*nrows floats
    float* tot     = partial + (size_t)64 * nrows;                 // 64 floats

    prep_k<<<KK + nblk32, 256, 0, stream>>>(data_in, weight, xTb, wTb, N);
    conv_k<<<nblk64, 256, 0, stream>>>(xTb, neigh, wTb, out, partial, N, nrows);
    stats1_k<<<64, 256, 0, stream>>>(partial, nrows, tot);
    dim3 ngrid(((N + 3) / 4 + 255) / 256, 32);
    norm_k<<<ngrid, 256, 0, stream>>>(out, tot, gamma, beta, N);
}